// Round 12
// baseline (355.018 us; speedup 1.0000x reference)
//
#include <hip/hip_runtime.h>
#include <math.h>

typedef unsigned short u16;
typedef unsigned int u32;
typedef __attribute__((ext_vector_type(8))) short short8;
typedef __attribute__((ext_vector_type(4))) short short4v;
typedef __attribute__((ext_vector_type(4))) float f32x4;

// Problem constants
constexpr int Bc = 8;
constexpr int Tt = 1025;
constexpr int Cc = 512;
constexpr int Hn = 8;
constexpr int CA = 256;
constexpr int Ll = 256;

#if __has_builtin(__builtin_amdgcn_exp2f)
#define EXP2F __builtin_amdgcn_exp2f
#else
#define EXP2F exp2f
#endif

__device__ __forceinline__ u16 f2bf(float f) {
  u32 u = __builtin_bit_cast(u32, f);
  u = (u + 0x7FFFu + ((u >> 16) & 1u)) >> 16;
  return (u16)u;
}
// fast pack two fp32 -> bf16x2 (round-half-up): one v_perm
__device__ __forceinline__ u32 pack2f(float lo, float hi) {
  const u32 a = __builtin_bit_cast(u32, hi) + 0x8000u;
  const u32 b = __builtin_bit_cast(u32, lo) + 0x8000u;
  return __builtin_amdgcn_perm(a, b, 0x07060302u);
}

// async global->LDS DMA, 16 B per lane.
__device__ __forceinline__ void gld16(void* lds, const void* g) {
  __builtin_amdgcn_global_load_lds(
      (const __attribute__((address_space(1))) u32*)g,
      (__attribute__((address_space(3))) u32*)lds, 16, 0, 0);
}

// Bijective XCD-chunked block remap (m204).  Consecutive work-ids share
// operand panels -> served by one XCD's L2 (r5: attn FETCH 70->12 MB).
__device__ __forceinline__ int xcd_work() {
  const int nwg = gridDim.x * gridDim.y;
  const int hw = blockIdx.y * gridDim.x + blockIdx.x;
  const int q = nwg >> 3, r = nwg & 7;
  const int xcd = hw & 7, pos = hw >> 3;
  const int base = (xcd < r) ? xcd * (q + 1) : r * (q + 1) + (xcd - r) * q;
  return base + pos;
}

// ---------------------------------------------------------------------------
// Weight cast+transpose into fused layouts: dst[n][k] = k<sK ? W[k][n] : 0
// ---------------------------------------------------------------------------
struct WC { const float* s; u16* d; int sN; int sK; int kshift; int tot; };
struct WCP { WC w[11]; };

__global__ void wcast_k(WCP p) {
  const WC a = p.w[blockIdx.y];
  const int kmask = (1 << a.kshift) - 1;
  for (int idx = blockIdx.x * 256 + threadIdx.x; idx < a.tot; idx += gridDim.x * 256) {
    const int k = idx & kmask;
    const int n = idx >> a.kshift;
    a.d[idx] = (k < a.sK) ? f2bf(a.s[(size_t)k * a.sN + n]) : (u16)0;
  }
}

// x [8200][512] f32 -> xb bf16, vectorized (float4 x2 -> short8).
__global__ __launch_bounds__(256) void xcast_k(const float* __restrict__ x,
                                               u16* __restrict__ xb)
{
  const size_t base = ((size_t)blockIdx.x * 256 + threadIdx.x) * 8;
  if (base >= (size_t)8200 * 512) return;
  const float4 f0 = *(const float4*)(x + base);
  const float4 f1 = *(const float4*)(x + base + 4);
  short8 w;
  ((u32*)&w)[0] = pack2f(f0.x, f0.y);
  ((u32*)&w)[1] = pack2f(f0.z, f0.w);
  ((u32*)&w)[2] = pack2f(f1.x, f1.y);
  ((u32*)&w)[3] = pack2f(f1.z, f1.w);
  *(short8*)(xb + base) = w;
}

// zero two f32 regions (attn1 accumulators)
__global__ __launch_bounds__(256) void zero2_k(float4* a, int na4, float4* b, int nb4)
{
  const int i = blockIdx.x * 256 + threadIdx.x;
  const float4 z = make_float4(0.f, 0.f, 0.f, 0.f);
  if (i < na4) a[i] = z;
  const int j = i - na4;
  if (j >= 0 && j < nb4) b[j] = z;
}

// att1 = bf16(xacc / lacc) ; xacc [8200][512] f32, lacc [b*8+h][1025]
__global__ __launch_bounds__(256) void attnorm_k(const float* __restrict__ xacc,
                                                 const float* __restrict__ lacc,
                                                 u16* __restrict__ att1)
{
  const size_t base = ((size_t)blockIdx.x * 256 + threadIdx.x) * 8;
  if (base >= (size_t)8200 * 512) return;
  const int row = (int)(base >> 9);
  const int col = (int)(base & 511);
  const int b = row / 1025;
  const int q = row - b * 1025;
  const int h = col >> 6;
  const float linv = 1.f / lacc[(b * 8 + h) * 1025 + q];
  const float4 f0 = *(const float4*)(xacc + base);
  const float4 f1 = *(const float4*)(xacc + base + 4);
  u16 w[8];
  w[0] = f2bf(f0.x * linv); w[1] = f2bf(f0.y * linv);
  w[2] = f2bf(f0.z * linv); w[3] = f2bf(f0.w * linv);
  w[4] = f2bf(f1.x * linv); w[5] = f2bf(f1.y * linv);
  w[6] = f2bf(f1.z * linv); w[7] = f2bf(f1.w * linv);
  *(short8*)(att1 + base) = *(short8*)w;
}

// ---------------------------------------------------------------------------
// bf16 MFMA GEMM, tile 128x128, K-chunking NH*32 per iteration.
// r10-proven pipeline: reads(t) -> sched_barrier(0) -> issue DMA(t+1) into
// OTHER buffer -> MFMAs(t) -> ONE barrier.
// NH=1 -> 32 KB LDS (mega resident); NH=2 -> 64 KB (small grids).
// ---------------------------------------------------------------------------
enum { EP_NONE = 0, EP_SIGMOID = 1, EP_GELU = 2 };

struct GemmEpi {
  const float* bias[4];
  int start[4];
  float scale[4];
  int nreg;
};

template <int OUTBF, int ACT, int NH>
__global__ __launch_bounds__(256) void gemm_mfma(
    const void* __restrict__ Av, int lda,
    const u16* __restrict__ Wt,
    GemmEpi epi,
    void* __restrict__ Cout,
    int M, int N, int K)
{
  __shared__ __align__(16) u16 As[2][NH][128][32];
  __shared__ __align__(16) u16 Bs[2][NH][128][32];
  const int tid = threadIdx.x;
  const int work = xcd_work();
  const int m0 = (work / gridDim.x) * 128, n0 = (work % gridDim.x) * 128;
  const int ln = tid & 15, quad = (tid >> 4) & 3, wv = tid >> 6;
  const int wm = (wv & 1) * 64, wn = (wv >> 1) * 64;
  const int lane = tid & 63;
  const int grow = wv * 32 + (lane >> 2);
  const int gcol = (lane & 3) * 8;

  f32x4 zf = {0.f, 0.f, 0.f, 0.f};
  f32x4 acc[4][4];
  #pragma unroll
  for (int i = 0; i < 4; i++)
    #pragma unroll
    for (int j = 0; j < 4; j++) acc[i][j] = zf;

  auto issueA = [&](int t, int db) {
    const int k0 = t * (NH * 32);
    #pragma unroll
    for (int h = 0; h < NH; h++)
      #pragma unroll
      for (int i = 0; i < 2; i++)
        gld16(&As[db][h][wv * 32 + i * 16][0],
              (const u16*)Av + (size_t)(m0 + grow + i * 16) * lda + k0 + h * 32 + gcol);
  };
  auto issueB = [&](int t, int db) {
    const int k0 = t * (NH * 32);
    #pragma unroll
    for (int h = 0; h < NH; h++)
      #pragma unroll
      for (int i = 0; i < 2; i++)
        gld16(&Bs[db][h][wv * 32 + i * 16][0],
              Wt + (size_t)(n0 + grow + i * 16) * K + k0 + h * 32 + gcol);
  };

  const int NT = K / (NH * 32);
  issueA(0, 0);
  issueB(0, 0);
  __syncthreads();
  for (int t = 0; t < NT; t++) {
    const int db = t & 1;
    short8 af[NH][4], bf[NH][4];
    #pragma unroll
    for (int h = 0; h < NH; h++) {
      #pragma unroll
      for (int i = 0; i < 4; i++) af[h][i] = *(const short8*)&As[db][h][wm + i * 16 + ln][quad * 8];
      #pragma unroll
      for (int j = 0; j < 4; j++) bf[h][j] = *(const short8*)&Bs[db][h][wn + j * 16 + ln][quad * 8];
    }
    __builtin_amdgcn_sched_barrier(0);
    if (t + 1 < NT) { issueA(t + 1, db ^ 1); issueB(t + 1, db ^ 1); }
    #pragma unroll
    for (int h = 0; h < NH; h++)
      #pragma unroll
      for (int i = 0; i < 4; i++)
        #pragma unroll
        for (int j = 0; j < 4; j++)
          acc[i][j] = __builtin_amdgcn_mfma_f32_16x16x32_bf16(af[h][i], bf[h][j], acc[i][j], 0, 0, 0);
    if (t + 1 < NT) __syncthreads();
  }

  int ri = 0;
  #pragma unroll
  for (int i = 1; i < 4; i++)
    if (i < epi.nreg && epi.start[i] <= n0) ri = i;
  const float* bp = epi.bias[ri] - epi.start[ri];
  const float sc = epi.scale[ri];

  float bj[4];
  #pragma unroll
  for (int j = 0; j < 4; j++) bj[j] = bp[n0 + wn + j * 16 + ln];

  #pragma unroll
  for (int i = 0; i < 4; i++) {
    #pragma unroll
    for (int r = 0; r < 4; r++) {
      const int gm = m0 + wm + i * 16 + quad * 4 + r;
      if (gm >= M) continue;
      #pragma unroll
      for (int j = 0; j < 4; j++) {
        float v = (acc[i][j][r] + bj[j]) * sc;
        if (ACT == EP_SIGMOID)   v = 1.f / (1.f + __expf(-v));
        else if (ACT == EP_GELU) v = 0.5f * v * (1.f + erff(v * 0.70710678118654752f));
        const size_t off = (size_t)gm * N + n0 + wn + j * 16 + ln;
        if (OUTBF) ((u16*)Cout)[off] = f2bf(v);
        else       ((float*)Cout)[off] = v;
      }
    }
  }
}

// ---------------------------------------------------------------------------
// MFMA flash attention v7 inner loop (FROZEN: r2/r3/r8 restructures all
// regressed) + optional GRID-LEVEL key split (SPLIT=1, flash-decode):
// grid.z=2, segment seg = z*2+pair gets nit/4 iterations; partials are
// atomically accumulated into a zeroed f32 buffer (exactly 2 commutative
// adds/element -> bit-exact deterministic); attnorm_k normalizes to bf16.
// Inner loop, LDS layout, prefetch placement are byte-identical to v7.
// ---------------------------------------------------------------------------
template <int DH, int SPLIT>
__global__ __launch_bounds__(256) void attn_mfma(
    const u16* __restrict__ Qp, const u16* __restrict__ Kp,
    const u16* __restrict__ Vp, u16* __restrict__ Op,
    float* __restrict__ Xa, float* __restrict__ La,
    int Tq, int Tk, int qbs, int kbs, int obs, int qrs, int krs, int ors)
{
  constexpr int NC = DH / 32;      // score k-chunks
  constexpr int NM = DH / 16;      // output d-tiles
  constexpr int VTE = 2 * DH * 32; // u16 elems per pair (dbuf x DH x 32)
  constexpr int PAY = 2 * NM * 4 + 2;   // combine payload floats/lane
  constexpr int PSTR = PAY | 1;         // odd stride -> conflict-free b32

  __shared__ __align__(16) char smem[2 * VTE * 2 + 4 * 1024 * 2];
  static_assert(128 * PSTR * 4 <= 2 * VTE * 2 + 4 * 1024 * 2, "combine fits");
  u16* const VtP = (u16*)smem;                    // [pair][db][DH*32]
  u16* const PbP = (u16*)(smem + 2 * VTE * 2);    // [wv][1024]

  const int work = xcd_work();
  const int bh = work / gridDim.x;
  const int b = bh >> 3, h = bh & 7;
  const int q0 = (work % gridDim.x) * 64;
  const int z = SPLIT ? blockIdx.z : 0;
  const int tid = threadIdx.x;
  const int wv = tid >> 6;
  const int pair = wv >> 1;        // key-split half (within block)
  const int wvp = wv & 1;          // wave within pair -> q rows
  const int lane = tid & 63;
  const int ln = lane & 15, quad = lane >> 4;
  const int lt = tid & 127;        // thread within pair (V staging)

  const u16* Qb = Qp + (size_t)b * qbs + h * DH;
  const u16* Kb = Kp + (size_t)b * kbs + h * DH;
  const u16* Vb = Vp + (size_t)b * kbs + h * DH;
  u16* Ob = Op + (size_t)b * obs + h * DH;

  const short8 z8 = {0, 0, 0, 0, 0, 0, 0, 0};
  const f32x4 zf = {0.f, 0.f, 0.f, 0.f};

  // Q fragments (B-operand = Q^T), resident across K loop
  short8 qf[2][NC];
  #pragma unroll
  for (int qs = 0; qs < 2; qs++) {
    const int gq = q0 + wvp * 32 + qs * 16 + ln;
    #pragma unroll
    for (int c = 0; c < NC; c++) {
      if (gq < Tq) qf[qs][c] = *(const short8*)(Qb + (size_t)gq * qrs + c * 32 + quad * 8);
      else         qf[qs][c] = z8;
    }
  }

  f32x4 oacc[2][NM];
  float lsum[2] = {0.f, 0.f};
  #pragma unroll
  for (int qs = 0; qs < 2; qs++)
    #pragma unroll
    for (int c = 0; c < NM; c++) oacc[qs][c] = zf;

  // V staging maps (within pair)
  const int vd0 = (lt & 15) * (DH / 16);
  const int vk = (lt >> 4) * 4;
  const int gb = vk >> 3, off = vk & 7;

  const int nfull = Tk >> 5;
  const int nit = (Tk + 31) >> 5;
  const int tkm1 = Tk - 1;
  const int nseg = SPLIT ? 4 : 2;
  const int np = (nit + nseg - 1) / nseg;   // iters per segment (pad-masked)
  const int seg = SPLIT ? (z * 2 + pair) : pair;
  const int it0 = seg * np;
  const int itE = it0 + np;

  // branch-free prefetchers (row clamped to Tk-1)
  auto loadK = [&](int it, short8 (&kf)[2][NC]) {
    #pragma unroll
    for (int kc = 0; kc < 2; kc++)
      #pragma unroll
      for (int c = 0; c < NC; c++) {
        int row = (it << 5) + kc * 16 + ln;
        row = row < tkm1 ? row : tkm1;
        kf[kc][c] = *(const short8*)(Kb + (size_t)row * krs + c * 32 + quad * 8);
      }
  };
  auto loadV = [&](int it, short4v (&vr)[4]) {
    #pragma unroll
    for (int i2 = 0; i2 < 4; i2++) {
      int gk = (it << 5) + vk + i2;
      gk = gk < tkm1 ? gk : tkm1;
      short4v t = {0, 0, 0, 0};
      if (DH == 64) {
        t = *(const short4v*)(Vb + (size_t)gk * krs + vd0);
      } else {
        ushort2 u = *(const ushort2*)(Vb + (size_t)gk * krs + vd0);
        t[0] = (short)u.x; t[1] = (short)u.y;
      }
      vr[i2] = t;
    }
  };

  auto body = [&](int it, short8 (&kfC)[2][NC], short4v (&vrC)[4],
                  short8 (&kfN)[2][NC], short4v (&vrN)[4]) {
    const bool full = (it < nfull);
    u16* vt = VtP + pair * VTE + (it & 1) * (DH * 32);
    const int k0 = it << 5;

    // ---- stage V (from prefetched regs) into pair's Vt[it&1], swizzled b64 ----
    #pragma unroll
    for (int i = 0; i < DH / 16; i++) {
      const int d = vd0 + i;
      const int h2 = (d ^ (d >> 3)) & 3;
      short4v w = {vrC[0][i], vrC[1][i], vrC[2][i], vrC[3][i]};
      *(short4v*)&vt[d * 32 + ((gb ^ h2) << 3) + off] = w;
    }
    // ---- prefetch next iteration (overlaps with compute below) ----
    if (it + 1 < itE) { loadK(it + 1, kfN); loadV(it + 1, vrN); }
    __syncthreads();

    // ---- scores S^T, exp2, pack P (swizzled b64 writes) ----
    #pragma unroll
    for (int qs = 0; qs < 2; qs++) {
      #pragma unroll
      for (int kc = 0; kc < 2; kc++) {
        f32x4 s = zf;
        #pragma unroll
        for (int c = 0; c < NC; c++)
          s = __builtin_amdgcn_mfma_f32_16x16x32_bf16(kfC[kc][c], qf[qs][c], s, 0, 0, 0);
        float p0, p1, p2, p3;
        if (full) {
          p0 = EXP2F(s[0]); p1 = EXP2F(s[1]); p2 = EXP2F(s[2]); p3 = EXP2F(s[3]);
        } else {
          const int kb = k0 + kc * 16 + quad * 4;
          p0 = (kb + 0 < Tk) ? EXP2F(s[0]) : 0.f;
          p1 = (kb + 1 < Tk) ? EXP2F(s[1]) : 0.f;
          p2 = (kb + 2 < Tk) ? EXP2F(s[2]) : 0.f;
          p3 = (kb + 3 < Tk) ? EXP2F(s[3]) : 0.f;
        }
        lsum[qs] += (p0 + p1) + (p2 + p3);
        short4v pw;
        ((u32*)&pw)[0] = pack2f(p0, p1);
        ((u32*)&pw)[1] = pack2f(p2, p3);
        const int q = qs * 16 + ln;
        const int g = ((kc * 2 + (quad >> 1)) ^ (ln & 3)) & 3;
        *(short4v*)&PbP[wv * 1024 + q * 32 + (g << 3) + (quad & 1) * 4] = pw;
      }
    }

    // ---- PV: O += P.V (per-wave Pb, no barrier) ----
    short8 pf2[2];
    #pragma unroll
    for (int qs = 0; qs < 2; qs++) {
      const int q = qs * 16 + ln;
      const int g = quad ^ (ln & 3);
      pf2[qs] = *(const short8*)&PbP[wv * 1024 + q * 32 + g * 8];
    }
    #pragma unroll
    for (int c = 0; c < NM; c++) {
      const int d = c * 16 + ln;
      const int g = quad ^ ((d ^ (d >> 3)) & 3);
      const short8 vf = *(const short8*)&vt[d * 32 + g * 8];
      #pragma unroll
      for (int qs = 0; qs < 2; qs++)
        oacc[qs][c] = __builtin_amdgcn_mfma_f32_16x16x32_bf16(pf2[qs], vf, oacc[qs][c], 0, 0, 0);
    }
  };

  short8 kfA[2][NC], kfB[2][NC];
  short4v vrA[4], vrB[4];
  loadK(it0, kfA);
  loadV(it0, vrA);

  int j = it0;
  for (; j + 1 < itE; j += 2) {
    body(j, kfA, vrA, kfB, vrB);
    body(j + 1, kfB, vrB, kfA, vrA);
  }
  if (j < itE) body(j, kfA, vrA, kfB, vrB);

  // ---- cross-pair combine: upper pair dumps partials, lower pair adds ----
  __syncthreads();
  float* const cbuf = (float*)smem;
  if (wv >= 2) {
    float* dst = cbuf + ((wv - 2) * 64 + lane) * PSTR;
    int idx = 0;
    #pragma unroll
    for (int qs = 0; qs < 2; qs++)
      #pragma unroll
      for (int c = 0; c < NM; c++)
        #pragma unroll
        for (int r = 0; r < 4; r++) dst[idx++] = oacc[qs][c][r];
    dst[idx++] = lsum[0];
    dst[idx]   = lsum[1];
  }
  __syncthreads();
  if (wv >= 2) return;
  {
    const float* src = cbuf + (wv * 64 + lane) * PSTR;
    int idx = 0;
    #pragma unroll
    for (int qs = 0; qs < 2; qs++)
      #pragma unroll
      for (int c = 0; c < NM; c++)
        #pragma unroll
        for (int r = 0; r < 4; r++) oacc[qs][c][r] += src[idx++];
    lsum[0] += src[idx++];
    lsum[1] += src[idx];
  }

  // ---- per-row l (reduce across quads) ----
  float lq[2];
  #pragma unroll
  for (int qs = 0; qs < 2; qs++) {
    float t = lsum[qs];
    t += __shfl_xor(t, 16);
    t += __shfl_xor(t, 32);
    lq[qs] = t;
  }

  if (SPLIT) {
    // ---- flash-decode epilogue: atomic-accumulate f32 partials ----
    float* xa = Xa + (size_t)b * Tq * ors + h * DH;
    float* la = La + (size_t)bh * Tq;
    #pragma unroll
    for (int qs = 0; qs < 2; qs++) {
      #pragma unroll
      for (int r = 0; r < 4; r++) {
        const float lrow = __shfl(lq[qs], quad * 4 + r);
        const int gq = q0 + wvp * 32 + qs * 16 + quad * 4 + r;
        if (gq >= Tq) continue;
        if (ln == 0) atomicAdd(la + gq, lrow);
        #pragma unroll
        for (int c = 0; c < NM; c++)
          atomicAdd(xa + (size_t)gq * ors + c * 16 + ln, oacc[qs][c][r]);
      }
    }
  } else {
    // ---- direct epilogue: divide, store bf16 ----
    #pragma unroll
    for (int qs = 0; qs < 2; qs++) {
      #pragma unroll
      for (int r = 0; r < 4; r++) {
        const float linv = 1.f / __shfl(lq[qs], quad * 4 + r);
        const int gq = q0 + wvp * 32 + qs * 16 + quad * 4 + r;
        if (gq >= Tq) continue;
        #pragma unroll
        for (int c = 0; c < NM; c++)
          Ob[(size_t)gq * ors + c * 16 + ln] = f2bf(oacc[qs][c][r] * linv);
      }
    }
  }
}

// ---------------------------------------------------------------------------
// FUSED grouped-conv (pos) + final combine (register-window sliding conv).
// ---------------------------------------------------------------------------
__global__ __launch_bounds__(256) void conv_combine(
    const float* __restrict__ x, const float* __restrict__ cw,
    const float* __restrict__ cb, const float* __restrict__ x_self,
    const float* __restrict__ x_mem, const float* __restrict__ lam,
    float* __restrict__ out)
{
  const int bh = blockIdx.x;               // b*32 + h
  const int b = bh >> 5, hh = bh & 31;
  const int c = (blockIdx.y << 8) + threadIdx.x;   // 0..511
  const int ci = c & ~1;
  const int dd = c & 63;
  const int h8 = c >> 6;
  const float alpha = 1.f / (1.f + __expf(-lam[h8]));
  const float bias = cb[c];

  float wgt[2][9];
  #pragma unroll
  for (int ch = 0; ch < 2; ch++)
    #pragma unroll
    for (int k = 0; k < 9; k++) wgt[ch][k] = cw[c * 18 + ch * 9 + k];

  const float* xrow[3];
  bool rv[3];
  #pragma unroll
  for (int r = 0; r < 3; r++) {
    const int h2 = hh + r - 1;
    rv[r] = (unsigned)h2 < 32u;
    xrow[r] = x + ((size_t)(b * Tt) + 1 + h2 * 32) * Cc + ci;
  }

  float2 win[3][3];
  #pragma unroll
  for (int r = 0; r < 3; r++) {
    win[r][0] = make_float2(0.f, 0.f);
    win[r][1] = rv[r] ? *(const float2*)(xrow[r]) : make_float2(0.f, 0.f);
  }

  const size_t bT = (size_t)b * Tt;
  for (int w = 0; w < 32; w++) {
    #pragma unroll
    for (int r = 0; r < 3; r++)
      win[r][2] = (rv[r] && w + 1 < 32) ? *(const float2*)(xrow[r] + (w + 1) * Cc)
                                        : make_float2(0.f, 0.f);
    float pos = bias;
    #pragma unroll
    for (int r = 0; r < 3; r++)
      #pragma unroll
      for (int col = 0; col < 3; col++) {
        pos += win[r][col].x * wgt[0][r * 3 + col];
        pos += win[r][col].y * wgt[1][r * 3 + col];
      }
    const size_t bt = bT + 1 + hh * 32 + w;
    const float mem = (dd < 32) ? x_mem[bt * 256 + h8 * 32 + dd] : 0.f;
    out[bt * 512 + c] = pos + alpha * mem + (1.f - alpha) * x_self[bt * 512 + c];
    #pragma unroll
    for (int r = 0; r < 3; r++) { win[r][0] = win[r][1]; win[r][1] = win[r][2]; }
  }

  if (hh == 0) {
    const float mem = (dd < 32) ? x_mem[bT * 256 + h8 * 32 + dd] : 0.f;
    out[bT * 512 + c] = alpha * mem + (1.f - alpha) * x_self[bT * 512 + c];
  }
}

// cat = [gr (bcast) | x_summary] bf16
__global__ void build_cat(const float* __restrict__ gr_cache,
                          const float* __restrict__ x_self,
                          u16* __restrict__ cat)
{
  const int idx = blockIdx.x * 256 + threadIdx.x;
  if (idx >= Bc * Ll * 512) return;
  const int k = idx & 511;
  const int bi = idx >> 9;
  const int i = bi & 255;
  const int b = bi >> 8;
  float v;
  if (k < 256) v = gr_cache[i * 256 + k];
  else         v = x_self[((size_t)(b * Tt + 4 * i)) * Cc + (k - 256)];
  cat[idx] = f2bf(v);
}

// cat[:, :256] = bf16(reset * gr); reset = rzg cols 0..255
__global__ void build_cat2(const float* __restrict__ gr_cache,
                           const float* __restrict__ rzg,
                           u16* __restrict__ cat)
{
  const int idx = blockIdx.x * 256 + threadIdx.x;
  if (idx >= Bc * Ll * 256) return;
  const int k = idx & 255;
  const int bi = idx >> 8;
  const int i = bi & 255;
  cat[(size_t)bi * 512 + k] = f2bf(gr_cache[i * 256 + k] * rzg[(size_t)bi * 512 + k]);
}

// LayerNorm + gate -> gr_new bf16 ; z = rzg cols 256..511
__device__ inline float block_sum256(float v, float* red)
{
  #pragma unroll
  for (int o = 32; o >= 1; o >>= 1) v += __shfl_down(v, o);
  const int wid = threadIdx.x >> 6;
  if ((threadIdx.x & 63) == 0) red[wid] = v;
  __syncthreads();
  const float t = red[0] + red[1] + red[2] + red[3];
  __syncthreads();
  return t;
}

__global__ __launch_bounds__(256) void ln_gate(
    const float* __restrict__ add_raw, const float* __restrict__ rzg,
    const float* __restrict__ gr_cache, const float* __restrict__ gamma,
    const float* __restrict__ beta, u16* __restrict__ gr_new)
{
  __shared__ float red[4];
  const int bi = blockIdx.x;
  const int i = bi & 255;
  const int c = threadIdx.x;
  const float v = add_raw[(size_t)bi * 256 + c];
  const float mu = block_sum256(v, red) * (1.f / 256.f);
  const float dv = v - mu;
  const float var = block_sum256(dv * dv, red) * (1.f / 256.f);
  const float nrm = dv * rsqrtf(var + 1e-5f) * gamma[c] + beta[c];
  const float zz = rzg[(size_t)bi * 512 + 256 + c];
  gr_new[(size_t)bi * 256 + c] = f2bf(zz * nrm + (1.f - zz) * gr_cache[i * 256 + c]);
}

// ---------------------------------------------------------------------------
extern "C" void kernel_launch(void* const* d_in, const int* in_sizes, int n_in,
                              void* d_out, int out_size, void* d_ws, size_t ws_size,
                              hipStream_t stream)
{
  const float* x        = (const float*)d_in[0];
  const float* gr_cache = (const float*)d_in[1];
  const float* Wq1 = (const float*)d_in[2];  const float* bq1 = (const float*)d_in[3];
  const float* Wk1 = (const float*)d_in[4];  const float* bk1 = (const float*)d_in[5];
  const float* Wv1 = (const float*)d_in[6];  const float* bv1 = (const float*)d_in[7];
  const float* Wo1 = (const float*)d_in[8];  const float* bo1 = (const float*)d_in[9];
  const float* Wq2 = (const float*)d_in[10]; const float* bq2 = (const float*)d_in[11];
  const float* Wk2 = (const float*)d_in[12]; const float* bk2 = (const float*)d_in[13];
  const float* Wv2 = (const float*)d_in[14]; const float* bv2 = (const float*)d_in[15];
  const float* Wo2 = (const float*)d_in[16]; const float* bo2 = (const float*)d_in[17];
  const float* Wr  = (const float*)d_in[18]; const float* br  = (const float*)d_in[19];
  const float* Wz  = (const float*)d_in[20]; const float* bz  = (const float*)d_in[21];
  const float* Wa  = (const float*)d_in[22]; const float* ba  = (const float*)d_in[23];
  const float* gamma = (const float*)d_in[24];
  const float* beta  = (const float*)d_in[25];
  const float* lam   = (const float*)d_in[26];
  const float* conv_w = (const float*)d_in[27];
  const float* conv_b = (const float*)d_in[28];
  float* out = (float*)d_out;

  const int M1 = Bc * Tt;       // 8200
  const int M2 = Bc * Ll;       // 2048
  const size_t BLA = (size_t)Bc * Ll * CA;
  const size_t BL2 = (size_t)Bc * Ll * 512;

  char* W = (char*)d_ws;
  u16*   qkvq  = (u16*)(W + 0);           // [8200][1792] = 29,388,800 B
  u16*   xb    = (u16*)(W + 29388800);    // bf16 x (att1 slot; dead after mega)
  u16*   att1  = (u16*)(W + 29388800);    // [8200][512] bf16 (after attnorm)
  u16*   att2  = (u16*)(W + 29388800);    // reuse (att1 dead after o1)
  float* xacc  = (float*)(W + 37785600);  // attn1 f32 accum [8200][512] (x_self slot)
  float* x_self= (float*)(W + 37785600);  // [8200][512] f32 (o1 output, after attnorm)
  u16*   cat   = (u16*)(W + 54579200);    // [2048][512] = 2,097,152
  float* rzg   = (float*)(W + 56676352);  // [2048][512] f32 = 4,194,304
  float* addr_ = (float*)(W + 60870656);  // [2048][256] f32 = 2,097,152
  float* x_mem = (float*)(W + 54579200);  // reuse cat/rzg/addr after ln_gate
  float* lacc  = (float*)(W + 62976000);  // attn1 lsum accum [64][1025] f32 (gr_new slot)
  u16*   gr_new= (u16*)(W + 62976000);    // [2048][256] (written by ln_gate, after attnorm)
  u16*   k2v2  = (u16*)(W + 64024576);    // [2048][512] = 2,097,152
  u16*   wtb   = (u16*)(W + 66121728);    // 3,538,944 B -> end 69,660,672

  u16* megaW = wtb;                 // [1792][512]
  u16* o1W   = wtb + 917504;        // [512][512]
  u16* rzW   = wtb + 1179648;       // [512][512]
  u16* aW    = wtb + 1441792;       // [256][512]
  u16* kvW   = wtb + 1572864;       // [512][256]
  u16* o2W   = wtb + 1703936;       // [256][256]

  const dim3 blk(256);

  // ---- weight casts into fused layouts ----
  {
    WCP p;
    p.w[0]  = {Wq1, megaW + 0,           512, 512, 9, 512 * 512};
    p.w[1]  = {Wk1, megaW + 512 * 512,   512, 512, 9, 512 * 512};
    p.w[2]  = {Wv1, megaW + 1024 * 512,  512, 512, 9, 512 * 512};
    p.w[3]  = {Wq2, megaW + 1536 * 512,  256, 256, 9, 256 * 512}; // zero-padded K
    p.w[4]  = {Wo1, o1W,                 512, 512, 9, 512 * 512};
    p.w[5]  = {Wr,  rzW + 0,             256, 512, 9, 256 * 512};
    p.w[6]  = {Wz,  rzW + 256 * 512,     256, 512, 9, 256 * 512};
    p.w[7]  = {Wa,  aW,                  256, 512, 9, 256 * 512};
    p.w[8]  = {Wk2, kvW + 0,             256, 256, 8, 256 * 256};
    p.w[9]  = {Wv2, kvW + 256 * 256,     256, 256, 8, 256 * 256};
    p.w[10] = {Wo2, o2W,                 256, 256, 8, 256 * 256};
    wcast_k<<<dim3(64, 11), blk, 0, stream>>>(p);
  }

  // ---- x -> bf16 (one-time) + zero attn1 accumulators ----
  xcast_k<<<dim3(2050), blk, 0, stream>>>(x, xb);
  zero2_k<<<dim3(4165), blk, 0, stream>>>((float4*)xacc, 8200 * 512 / 4,
                                          (float4*)lacc, 64 * 1025 / 4);

  const float sQ1 = 0.18033688011112042f;   // (1/8) * log2(e)
  const float sQ2 = 0.25503490664918414f;   // (1/sqrt(32)) * log2(e)

  // ---- mega QKV1+Q2 projection: bf16 xb -> bf16 qkvq[8200][1792] ----
  {
    GemmEpi e;
    e.bias[0] = bq1; e.start[0] = 0;    e.scale[0] = sQ1;
    e.bias[1] = bk1; e.start[1] = 512;  e.scale[1] = 1.f;
    e.bias[2] = bv1; e.start[2] = 1024; e.scale[2] = 1.f;
    e.bias[3] = bq2; e.start[3] = 1536; e.scale[3] = sQ2;
    e.nreg = 4;
    gemm_mfma<1, EP_NONE, 1><<<dim3(14, 65), blk, 0, stream>>>(
        xb, 512, megaW, e, qkvq, M1, 1792, 512);
  }

  // ---- attention 1 (flash-decode z=2 split; partials -> xacc/lacc) ----
  attn_mfma<64, 1><<<dim3(17, 64, 2), dim3(256), 0, stream>>>(
      qkvq, qkvq + 512, qkvq + 1024, att1, xacc, lacc, Tt, Tt,
      Tt * 1792, Tt * 1792, Tt * 512, 1792, 1792, 512);
  attnorm_k<<<dim3(2050), blk, 0, stream>>>(xacc, lacc, att1);

  // ---- o-proj 1 -> x_self fp32 ----
  {
    GemmEpi e; e.bias[0] = bo1; e.start[0] = 0; e.scale[0] = 1.f; e.nreg = 1;
    gemm_mfma<0, EP_NONE, 2><<<dim3(4, 65), blk, 0, stream>>>(
        att1, 512, o1W, e, x_self, M1, 512, 512);
  }

  // ---- GRU cache update ----
  build_cat<<<(int)((BL2 + 255) / 256), blk, 0, stream>>>(gr_cache, x_self, cat);
  {
    GemmEpi e;
    e.bias[0] = br; e.start[0] = 0;   e.scale[0] = 1.f;
    e.bias[1] = bz; e.start[1] = 256; e.scale[1] = 1.f;
    e.nreg = 2;
    gemm_mfma<0, EP_SIGMOID, 2><<<dim3(4, 16), blk, 0, stream>>>(
        cat, 512, rzW, e, rzg, M2, 512, 512);
  }
  build_cat2<<<(int)((BLA + 255) / 256), blk, 0, stream>>>(gr_cache, rzg, cat);
  {
    GemmEpi e; e.bias[0] = ba; e.start[0] = 0; e.scale[0] = 1.f; e.nreg = 1;
    gemm_mfma<0, EP_GELU, 2><<<dim3(2, 16), blk, 0, stream>>>(
        cat, 512, aW, e, addr_, M2, 256, 512);
  }
  ln_gate<<<M2, blk, 0, stream>>>(addr_, rzg, gr_cache, gamma, beta, gr_new);

  // ---- K2|V2 projection (fused) ----
  {
    GemmEpi e;
    e.bias[0] = bk2; e.start[0] = 0;   e.scale[0] = 1.f;
    e.bias[1] = bv2; e.start[1] = 256; e.scale[1] = 1.f;
    e.nreg = 2;
    gemm_mfma<1, EP_NONE, 2><<<dim3(4, 16), blk, 0, stream>>>(
        gr_new, 256, kvW, e, k2v2, M2, 512, 256);
  }

  // ---- attention 2 (q from qkvq cols 1536.., kv from k2v2; unsplit) ----
  attn_mfma<32, 0><<<dim3(17, 64), dim3(256), 0, stream>>>(
      qkvq + 1536, k2v2, k2v2 + 256, att2, nullptr, nullptr, Tt, Ll,
      Tt * 1792, Ll * 512, Tt * 256, 1792, 512, 256);

  // ---- o-proj 2 -> x_mem fp32 ----
  {
    GemmEpi e; e.bias[0] = bo2; e.start[0] = 0; e.scale[0] = 1.f; e.nreg = 1;
    gemm_mfma<0, EP_NONE, 2><<<dim3(2, 65), blk, 0, stream>>>(
        att2, 256, o2W, e, x_mem, M1, 256, 256);
  }

  // ---- fused conv(pos) + final mix -> d_out ----
  conv_combine<<<dim3(Bc * 32, 2), blk, 0, stream>>>(x, conv_w, conv_b, x_self,
                                                     x_mem, lam, out);
}

// Round 13
// 329.453 us; speedup vs baseline: 1.0776x; 1.0776x over previous
//
#include <hip/hip_runtime.h>
#include <math.h>

typedef unsigned short u16;
typedef unsigned int u32;
typedef __attribute__((ext_vector_type(8))) short short8;
typedef __attribute__((ext_vector_type(4))) short short4v;
typedef __attribute__((ext_vector_type(4))) float f32x4;

// Problem constants
constexpr int Bc = 8;
constexpr int Tt = 1025;
constexpr int Cc = 512;
constexpr int Hn = 8;
constexpr int CA = 256;
constexpr int Ll = 256;

#if __has_builtin(__builtin_amdgcn_exp2f)
#define EXP2F __builtin_amdgcn_exp2f
#else
#define EXP2F exp2f
#endif

__device__ __forceinline__ u16 f2bf(float f) {
  u32 u = __builtin_bit_cast(u32, f);
  u = (u + 0x7FFFu + ((u >> 16) & 1u)) >> 16;
  return (u16)u;
}
// fast pack two fp32 -> bf16x2 (round-half-up): one v_perm
__device__ __forceinline__ u32 pack2f(float lo, float hi) {
  const u32 a = __builtin_bit_cast(u32, hi) + 0x8000u;
  const u32 b = __builtin_bit_cast(u32, lo) + 0x8000u;
  return __builtin_amdgcn_perm(a, b, 0x07060302u);
}

// async global->LDS DMA, 16 B per lane.
__device__ __forceinline__ void gld16(void* lds, const void* g) {
  __builtin_amdgcn_global_load_lds(
      (const __attribute__((address_space(1))) u32*)g,
      (__attribute__((address_space(3))) u32*)lds, 16, 0, 0);
}

// Bijective XCD-chunked block remap (m204).  Consecutive work-ids share
// operand panels -> served by one XCD's L2 (r5: attn FETCH 70->12 MB).
__device__ __forceinline__ int xcd_work() {
  const int nwg = gridDim.x * gridDim.y;
  const int hw = blockIdx.y * gridDim.x + blockIdx.x;
  const int q = nwg >> 3, r = nwg & 7;
  const int xcd = hw & 7, pos = hw >> 3;
  const int base = (xcd < r) ? xcd * (q + 1) : r * (q + 1) + (xcd - r) * q;
  return base + pos;
}

// ---------------------------------------------------------------------------
// Weight cast+transpose into fused layouts: dst[n][k] = k<sK ? W[k][n] : 0
// ---------------------------------------------------------------------------
struct WC { const float* s; u16* d; int sN; int sK; int kshift; int tot; };
struct WCP { WC w[11]; };

__global__ void wcast_k(WCP p) {
  const WC a = p.w[blockIdx.y];
  const int kmask = (1 << a.kshift) - 1;
  for (int idx = blockIdx.x * 256 + threadIdx.x; idx < a.tot; idx += gridDim.x * 256) {
    const int k = idx & kmask;
    const int n = idx >> a.kshift;
    a.d[idx] = (k < a.sK) ? f2bf(a.s[(size_t)k * a.sN + n]) : (u16)0;
  }
}

// x [8200][512] f32 -> xb bf16, vectorized (float4 x2 -> short8).
__global__ __launch_bounds__(256) void xcast_k(const float* __restrict__ x,
                                               u16* __restrict__ xb)
{
  const size_t base = ((size_t)blockIdx.x * 256 + threadIdx.x) * 8;
  if (base >= (size_t)8200 * 512) return;
  const float4 f0 = *(const float4*)(x + base);
  const float4 f1 = *(const float4*)(x + base + 4);
  short8 w;
  ((u32*)&w)[0] = pack2f(f0.x, f0.y);
  ((u32*)&w)[1] = pack2f(f0.z, f0.w);
  ((u32*)&w)[2] = pack2f(f1.x, f1.y);
  ((u32*)&w)[3] = pack2f(f1.z, f1.w);
  *(short8*)(xb + base) = w;
}

// ---------------------------------------------------------------------------
// bf16 MFMA GEMM, tile 128x128, K-chunking NH*32 per iteration.
// r10-proven pipeline: reads(t) -> sched_barrier(0) -> issue DMA(t+1) into
// OTHER buffer -> MFMAs(t) -> ONE barrier.
// NH=1 -> 32 KB LDS (mega resident); NH=2 -> 64 KB (small grids).
// ---------------------------------------------------------------------------
enum { EP_NONE = 0, EP_SIGMOID = 1, EP_GELU = 2 };

struct GemmEpi {
  const float* bias[4];
  int start[4];
  float scale[4];
  int nreg;
};

template <int OUTBF, int ACT, int NH>
__global__ __launch_bounds__(256) void gemm_mfma(
    const void* __restrict__ Av, int lda,
    const u16* __restrict__ Wt,
    GemmEpi epi,
    void* __restrict__ Cout,
    int M, int N, int K)
{
  __shared__ __align__(16) u16 As[2][NH][128][32];
  __shared__ __align__(16) u16 Bs[2][NH][128][32];
  const int tid = threadIdx.x;
  const int work = xcd_work();
  const int m0 = (work / gridDim.x) * 128, n0 = (work % gridDim.x) * 128;
  const int ln = tid & 15, quad = (tid >> 4) & 3, wv = tid >> 6;
  const int wm = (wv & 1) * 64, wn = (wv >> 1) * 64;
  const int lane = tid & 63;
  const int grow = wv * 32 + (lane >> 2);
  const int gcol = (lane & 3) * 8;

  f32x4 zf = {0.f, 0.f, 0.f, 0.f};
  f32x4 acc[4][4];
  #pragma unroll
  for (int i = 0; i < 4; i++)
    #pragma unroll
    for (int j = 0; j < 4; j++) acc[i][j] = zf;

  auto issueA = [&](int t, int db) {
    const int k0 = t * (NH * 32);
    #pragma unroll
    for (int h = 0; h < NH; h++)
      #pragma unroll
      for (int i = 0; i < 2; i++)
        gld16(&As[db][h][wv * 32 + i * 16][0],
              (const u16*)Av + (size_t)(m0 + grow + i * 16) * lda + k0 + h * 32 + gcol);
  };
  auto issueB = [&](int t, int db) {
    const int k0 = t * (NH * 32);
    #pragma unroll
    for (int h = 0; h < NH; h++)
      #pragma unroll
      for (int i = 0; i < 2; i++)
        gld16(&Bs[db][h][wv * 32 + i * 16][0],
              Wt + (size_t)(n0 + grow + i * 16) * K + k0 + h * 32 + gcol);
  };

  const int NT = K / (NH * 32);
  issueA(0, 0);
  issueB(0, 0);
  __syncthreads();
  for (int t = 0; t < NT; t++) {
    const int db = t & 1;
    short8 af[NH][4], bf[NH][4];
    #pragma unroll
    for (int h = 0; h < NH; h++) {
      #pragma unroll
      for (int i = 0; i < 4; i++) af[h][i] = *(const short8*)&As[db][h][wm + i * 16 + ln][quad * 8];
      #pragma unroll
      for (int j = 0; j < 4; j++) bf[h][j] = *(const short8*)&Bs[db][h][wn + j * 16 + ln][quad * 8];
    }
    __builtin_amdgcn_sched_barrier(0);
    if (t + 1 < NT) { issueA(t + 1, db ^ 1); issueB(t + 1, db ^ 1); }
    #pragma unroll
    for (int h = 0; h < NH; h++)
      #pragma unroll
      for (int i = 0; i < 4; i++)
        #pragma unroll
        for (int j = 0; j < 4; j++)
          acc[i][j] = __builtin_amdgcn_mfma_f32_16x16x32_bf16(af[h][i], bf[h][j], acc[i][j], 0, 0, 0);
    if (t + 1 < NT) __syncthreads();
  }

  int ri = 0;
  #pragma unroll
  for (int i = 1; i < 4; i++)
    if (i < epi.nreg && epi.start[i] <= n0) ri = i;
  const float* bp = epi.bias[ri] - epi.start[ri];
  const float sc = epi.scale[ri];

  float bj[4];
  #pragma unroll
  for (int j = 0; j < 4; j++) bj[j] = bp[n0 + wn + j * 16 + ln];

  #pragma unroll
  for (int i = 0; i < 4; i++) {
    #pragma unroll
    for (int r = 0; r < 4; r++) {
      const int gm = m0 + wm + i * 16 + quad * 4 + r;
      if (gm >= M) continue;
      #pragma unroll
      for (int j = 0; j < 4; j++) {
        float v = (acc[i][j][r] + bj[j]) * sc;
        if (ACT == EP_SIGMOID)   v = 1.f / (1.f + __expf(-v));
        else if (ACT == EP_GELU) v = 0.5f * v * (1.f + erff(v * 0.70710678118654752f));
        const size_t off = (size_t)gm * N + n0 + wn + j * 16 + ln;
        if (OUTBF) ((u16*)Cout)[off] = f2bf(v);
        else       ((float*)Cout)[off] = v;
      }
    }
  }
}

// ---------------------------------------------------------------------------
// MFMA flash attention v7 schedule (FROZEN: r2/r3/r8/r12 all regressed) with
// ONE physical-layout change: V-tile row stride padded 32 -> 40 u16 (80 B).
// r12 PMC: 8.9M bank-conflict cycles/dispatch = ~21% of CU time.  Cause: at
// stage-V unroll step i, all 16 lanes of a group write d = 4L'+i -> same
// d-parity, d*16 mod 32 constant -> ~8-way write conflict.  With stride 40,
// d*20 mod 32 alternates halves per lane and h2 spreads within -> 2-way
// (free, m136).  PV-read stays conflict-free.  Logical layout, schedule,
// math untouched.  LDS 24.5 -> 28.7 KB (still 5 blocks/CU).
// ---------------------------------------------------------------------------
template <int DH>
__global__ __launch_bounds__(256) void attn_mfma(
    const u16* __restrict__ Qp, const u16* __restrict__ Kp,
    const u16* __restrict__ Vp, u16* __restrict__ Op,
    int Tq, int Tk, int qbs, int kbs, int obs, int qrs, int krs, int ors)
{
  constexpr int NC = DH / 32;      // score k-chunks
  constexpr int NM = DH / 16;      // output d-tiles
  constexpr int VST = 40;          // padded V row stride (u16); was 32
  constexpr int VTE = 2 * DH * VST; // u16 elems per pair (dbuf x DH x VST)
  constexpr int PAY = 2 * NM * 4 + 2;   // combine payload floats/lane
  constexpr int PSTR = PAY | 1;         // odd stride -> conflict-free b32

  __shared__ __align__(16) char smem[2 * VTE * 2 + 4 * 1024 * 2];
  static_assert(128 * PSTR * 4 <= 2 * VTE * 2 + 4 * 1024 * 2, "combine fits");
  u16* const VtP = (u16*)smem;                    // [pair][db][DH*VST]
  u16* const PbP = (u16*)(smem + 2 * VTE * 2);    // [wv][1024]

  const int work = xcd_work();
  const int bh = work / gridDim.x;
  const int b = bh >> 3, h = bh & 7;
  const int q0 = (work % gridDim.x) * 64;
  const int tid = threadIdx.x;
  const int wv = tid >> 6;
  const int pair = wv >> 1;        // key-split half
  const int wvp = wv & 1;          // wave within pair -> q rows
  const int lane = tid & 63;
  const int ln = lane & 15, quad = lane >> 4;
  const int lt = tid & 127;        // thread within pair (V staging)

  const u16* Qb = Qp + (size_t)b * qbs + h * DH;
  const u16* Kb = Kp + (size_t)b * kbs + h * DH;
  const u16* Vb = Vp + (size_t)b * kbs + h * DH;
  u16* Ob = Op + (size_t)b * obs + h * DH;

  const short8 z8 = {0, 0, 0, 0, 0, 0, 0, 0};
  const f32x4 zf = {0.f, 0.f, 0.f, 0.f};

  // Q fragments (B-operand = Q^T), resident across K loop
  short8 qf[2][NC];
  #pragma unroll
  for (int qs = 0; qs < 2; qs++) {
    const int gq = q0 + wvp * 32 + qs * 16 + ln;
    #pragma unroll
    for (int c = 0; c < NC; c++) {
      if (gq < Tq) qf[qs][c] = *(const short8*)(Qb + (size_t)gq * qrs + c * 32 + quad * 8);
      else         qf[qs][c] = z8;
    }
  }

  f32x4 oacc[2][NM];
  float lsum[2] = {0.f, 0.f};
  #pragma unroll
  for (int qs = 0; qs < 2; qs++)
    #pragma unroll
    for (int c = 0; c < NM; c++) oacc[qs][c] = zf;

  // V staging maps (within pair)
  const int vd0 = (lt & 15) * (DH / 16);
  const int vk = (lt >> 4) * 4;
  const int gb = vk >> 3, off = vk & 7;

  const int nfull = Tk >> 5;
  const int nit = (Tk + 31) >> 5;
  const int tkm1 = Tk - 1;
  const int np = (nit + 1) >> 1;   // iters per pair (pair 1 may pad-mask)
  const int it0 = pair * np;
  const int itE = it0 + np;

  // branch-free prefetchers (row clamped to Tk-1)
  auto loadK = [&](int it, short8 (&kf)[2][NC]) {
    #pragma unroll
    for (int kc = 0; kc < 2; kc++)
      #pragma unroll
      for (int c = 0; c < NC; c++) {
        int row = (it << 5) + kc * 16 + ln;
        row = row < tkm1 ? row : tkm1;
        kf[kc][c] = *(const short8*)(Kb + (size_t)row * krs + c * 32 + quad * 8);
      }
  };
  auto loadV = [&](int it, short4v (&vr)[4]) {
    #pragma unroll
    for (int i2 = 0; i2 < 4; i2++) {
      int gk = (it << 5) + vk + i2;
      gk = gk < tkm1 ? gk : tkm1;
      short4v t = {0, 0, 0, 0};
      if (DH == 64) {
        t = *(const short4v*)(Vb + (size_t)gk * krs + vd0);
      } else {
        ushort2 u = *(const ushort2*)(Vb + (size_t)gk * krs + vd0);
        t[0] = (short)u.x; t[1] = (short)u.y;
      }
      vr[i2] = t;
    }
  };

  auto body = [&](int it, short8 (&kfC)[2][NC], short4v (&vrC)[4],
                  short8 (&kfN)[2][NC], short4v (&vrN)[4]) {
    const bool full = (it < nfull);
    u16* vt = VtP + pair * VTE + (it & 1) * (DH * VST);
    const int k0 = it << 5;

    // ---- stage V into pair's Vt[it&1], padded stride (2-way, conflict-free) ----
    #pragma unroll
    for (int i = 0; i < DH / 16; i++) {
      const int d = vd0 + i;
      const int h2 = (d ^ (d >> 3)) & 3;
      short4v w = {vrC[0][i], vrC[1][i], vrC[2][i], vrC[3][i]};
      *(short4v*)&vt[d * VST + ((gb ^ h2) << 3) + off] = w;
    }
    // ---- prefetch next iteration (overlaps with compute below) ----
    if (it + 1 < itE) { loadK(it + 1, kfN); loadV(it + 1, vrN); }
    __syncthreads();

    // ---- scores S^T, exp2, pack P (swizzled b64 writes) ----
    #pragma unroll
    for (int qs = 0; qs < 2; qs++) {
      #pragma unroll
      for (int kc = 0; kc < 2; kc++) {
        f32x4 s = zf;
        #pragma unroll
        for (int c = 0; c < NC; c++)
          s = __builtin_amdgcn_mfma_f32_16x16x32_bf16(kfC[kc][c], qf[qs][c], s, 0, 0, 0);
        float p0, p1, p2, p3;
        if (full) {
          p0 = EXP2F(s[0]); p1 = EXP2F(s[1]); p2 = EXP2F(s[2]); p3 = EXP2F(s[3]);
        } else {
          const int kb = k0 + kc * 16 + quad * 4;
          p0 = (kb + 0 < Tk) ? EXP2F(s[0]) : 0.f;
          p1 = (kb + 1 < Tk) ? EXP2F(s[1]) : 0.f;
          p2 = (kb + 2 < Tk) ? EXP2F(s[2]) : 0.f;
          p3 = (kb + 3 < Tk) ? EXP2F(s[3]) : 0.f;
        }
        lsum[qs] += (p0 + p1) + (p2 + p3);
        short4v pw;
        ((u32*)&pw)[0] = pack2f(p0, p1);
        ((u32*)&pw)[1] = pack2f(p2, p3);
        const int q = qs * 16 + ln;
        const int g = ((kc * 2 + (quad >> 1)) ^ (ln & 3)) & 3;
        *(short4v*)&PbP[wv * 1024 + q * 32 + (g << 3) + (quad & 1) * 4] = pw;
      }
    }

    // ---- PV: O += P.V (per-wave Pb, no barrier) ----
    short8 pf2[2];
    #pragma unroll
    for (int qs = 0; qs < 2; qs++) {
      const int q = qs * 16 + ln;
      const int g = quad ^ (ln & 3);
      pf2[qs] = *(const short8*)&PbP[wv * 1024 + q * 32 + g * 8];
    }
    #pragma unroll
    for (int c = 0; c < NM; c++) {
      const int d = c * 16 + ln;
      const int g = quad ^ ((d ^ (d >> 3)) & 3);
      const short8 vf = *(const short8*)&vt[d * VST + g * 8];
      #pragma unroll
      for (int qs = 0; qs < 2; qs++)
        oacc[qs][c] = __builtin_amdgcn_mfma_f32_16x16x32_bf16(pf2[qs], vf, oacc[qs][c], 0, 0, 0);
    }
  };

  short8 kfA[2][NC], kfB[2][NC];
  short4v vrA[4], vrB[4];
  loadK(it0, kfA);
  loadV(it0, vrA);

  int j = it0;
  for (; j + 1 < itE; j += 2) {
    body(j, kfA, vrA, kfB, vrB);
    body(j + 1, kfB, vrB, kfA, vrA);
  }
  if (j < itE) body(j, kfA, vrA, kfB, vrB);

  // ---- cross-pair combine: upper pair dumps partials, lower pair adds ----
  __syncthreads();
  float* const cbuf = (float*)smem;
  if (wv >= 2) {
    float* dst = cbuf + ((wv - 2) * 64 + lane) * PSTR;
    int idx = 0;
    #pragma unroll
    for (int qs = 0; qs < 2; qs++)
      #pragma unroll
      for (int c = 0; c < NM; c++)
        #pragma unroll
        for (int r = 0; r < 4; r++) dst[idx++] = oacc[qs][c][r];
    dst[idx++] = lsum[0];
    dst[idx]   = lsum[1];
  }
  __syncthreads();
  if (wv >= 2) return;
  {
    const float* src = cbuf + (wv * 64 + lane) * PSTR;
    int idx = 0;
    #pragma unroll
    for (int qs = 0; qs < 2; qs++)
      #pragma unroll
      for (int c = 0; c < NM; c++)
        #pragma unroll
        for (int r = 0; r < 4; r++) oacc[qs][c][r] += src[idx++];
    lsum[0] += src[idx++];
    lsum[1] += src[idx];
  }

  // ---- epilogue: reduce l across quads, divide, store ----
  float lq[2];
  #pragma unroll
  for (int qs = 0; qs < 2; qs++) {
    float t = lsum[qs];
    t += __shfl_xor(t, 16);
    t += __shfl_xor(t, 32);
    lq[qs] = t;
  }
  #pragma unroll
  for (int qs = 0; qs < 2; qs++) {
    #pragma unroll
    for (int r = 0; r < 4; r++) {
      const float linv = 1.f / __shfl(lq[qs], quad * 4 + r);
      const int gq = q0 + wvp * 32 + qs * 16 + quad * 4 + r;
      if (gq >= Tq) continue;
      #pragma unroll
      for (int c = 0; c < NM; c++)
        Ob[(size_t)gq * ors + c * 16 + ln] = f2bf(oacc[qs][c][r] * linv);
    }
  }
}

// ---------------------------------------------------------------------------
// FUSED grouped-conv (pos) + final combine (register-window sliding conv).
// ---------------------------------------------------------------------------
__global__ __launch_bounds__(256) void conv_combine(
    const float* __restrict__ x, const float* __restrict__ cw,
    const float* __restrict__ cb, const float* __restrict__ x_self,
    const float* __restrict__ x_mem, const float* __restrict__ lam,
    float* __restrict__ out)
{
  const int bh = blockIdx.x;               // b*32 + h
  const int b = bh >> 5, hh = bh & 31;
  const int c = (blockIdx.y << 8) + threadIdx.x;   // 0..511
  const int ci = c & ~1;
  const int dd = c & 63;
  const int h8 = c >> 6;
  const float alpha = 1.f / (1.f + __expf(-lam[h8]));
  const float bias = cb[c];

  float wgt[2][9];
  #pragma unroll
  for (int ch = 0; ch < 2; ch++)
    #pragma unroll
    for (int k = 0; k < 9; k++) wgt[ch][k] = cw[c * 18 + ch * 9 + k];

  const float* xrow[3];
  bool rv[3];
  #pragma unroll
  for (int r = 0; r < 3; r++) {
    const int h2 = hh + r - 1;
    rv[r] = (unsigned)h2 < 32u;
    xrow[r] = x + ((size_t)(b * Tt) + 1 + h2 * 32) * Cc + ci;
  }

  float2 win[3][3];
  #pragma unroll
  for (int r = 0; r < 3; r++) {
    win[r][0] = make_float2(0.f, 0.f);
    win[r][1] = rv[r] ? *(const float2*)(xrow[r]) : make_float2(0.f, 0.f);
  }

  const size_t bT = (size_t)b * Tt;
  for (int w = 0; w < 32; w++) {
    #pragma unroll
    for (int r = 0; r < 3; r++)
      win[r][2] = (rv[r] && w + 1 < 32) ? *(const float2*)(xrow[r] + (w + 1) * Cc)
                                        : make_float2(0.f, 0.f);
    float pos = bias;
    #pragma unroll
    for (int r = 0; r < 3; r++)
      #pragma unroll
      for (int col = 0; col < 3; col++) {
        pos += win[r][col].x * wgt[0][r * 3 + col];
        pos += win[r][col].y * wgt[1][r * 3 + col];
      }
    const size_t bt = bT + 1 + hh * 32 + w;
    const float mem = (dd < 32) ? x_mem[bt * 256 + h8 * 32 + dd] : 0.f;
    out[bt * 512 + c] = pos + alpha * mem + (1.f - alpha) * x_self[bt * 512 + c];
    #pragma unroll
    for (int r = 0; r < 3; r++) { win[r][0] = win[r][1]; win[r][1] = win[r][2]; }
  }

  if (hh == 0) {
    const float mem = (dd < 32) ? x_mem[bT * 256 + h8 * 32 + dd] : 0.f;
    out[bT * 512 + c] = alpha * mem + (1.f - alpha) * x_self[bT * 512 + c];
  }
}

// cat = [gr (bcast) | x_summary] bf16
__global__ void build_cat(const float* __restrict__ gr_cache,
                          const float* __restrict__ x_self,
                          u16* __restrict__ cat)
{
  const int idx = blockIdx.x * 256 + threadIdx.x;
  if (idx >= Bc * Ll * 512) return;
  const int k = idx & 511;
  const int bi = idx >> 9;
  const int i = bi & 255;
  const int b = bi >> 8;
  float v;
  if (k < 256) v = gr_cache[i * 256 + k];
  else         v = x_self[((size_t)(b * Tt + 4 * i)) * Cc + (k - 256)];
  cat[idx] = f2bf(v);
}

// cat[:, :256] = bf16(reset * gr); reset = rzg cols 0..255
__global__ void build_cat2(const float* __restrict__ gr_cache,
                           const float* __restrict__ rzg,
                           u16* __restrict__ cat)
{
  const int idx = blockIdx.x * 256 + threadIdx.x;
  if (idx >= Bc * Ll * 256) return;
  const int k = idx & 255;
  const int bi = idx >> 8;
  const int i = bi & 255;
  cat[(size_t)bi * 512 + k] = f2bf(gr_cache[i * 256 + k] * rzg[(size_t)bi * 512 + k]);
}

// LayerNorm + gate -> gr_new bf16 ; z = rzg cols 256..511
__device__ inline float block_sum256(float v, float* red)
{
  #pragma unroll
  for (int o = 32; o >= 1; o >>= 1) v += __shfl_down(v, o);
  const int wid = threadIdx.x >> 6;
  if ((threadIdx.x & 63) == 0) red[wid] = v;
  __syncthreads();
  const float t = red[0] + red[1] + red[2] + red[3];
  __syncthreads();
  return t;
}

__global__ __launch_bounds__(256) void ln_gate(
    const float* __restrict__ add_raw, const float* __restrict__ rzg,
    const float* __restrict__ gr_cache, const float* __restrict__ gamma,
    const float* __restrict__ beta, u16* __restrict__ gr_new)
{
  __shared__ float red[4];
  const int bi = blockIdx.x;
  const int i = bi & 255;
  const int c = threadIdx.x;
  const float v = add_raw[(size_t)bi * 256 + c];
  const float mu = block_sum256(v, red) * (1.f / 256.f);
  const float dv = v - mu;
  const float var = block_sum256(dv * dv, red) * (1.f / 256.f);
  const float nrm = dv * rsqrtf(var + 1e-5f) * gamma[c] + beta[c];
  const float zz = rzg[(size_t)bi * 512 + 256 + c];
  gr_new[(size_t)bi * 256 + c] = f2bf(zz * nrm + (1.f - zz) * gr_cache[i * 256 + c]);
}

// ---------------------------------------------------------------------------
extern "C" void kernel_launch(void* const* d_in, const int* in_sizes, int n_in,
                              void* d_out, int out_size, void* d_ws, size_t ws_size,
                              hipStream_t stream)
{
  const float* x        = (const float*)d_in[0];
  const float* gr_cache = (const float*)d_in[1];
  const float* Wq1 = (const float*)d_in[2];  const float* bq1 = (const float*)d_in[3];
  const float* Wk1 = (const float*)d_in[4];  const float* bk1 = (const float*)d_in[5];
  const float* Wv1 = (const float*)d_in[6];  const float* bv1 = (const float*)d_in[7];
  const float* Wo1 = (const float*)d_in[8];  const float* bo1 = (const float*)d_in[9];
  const float* Wq2 = (const float*)d_in[10]; const float* bq2 = (const float*)d_in[11];
  const float* Wk2 = (const float*)d_in[12]; const float* bk2 = (const float*)d_in[13];
  const float* Wv2 = (const float*)d_in[14]; const float* bv2 = (const float*)d_in[15];
  const float* Wo2 = (const float*)d_in[16]; const float* bo2 = (const float*)d_in[17];
  const float* Wr  = (const float*)d_in[18]; const float* br  = (const float*)d_in[19];
  const float* Wz  = (const float*)d_in[20]; const float* bz  = (const float*)d_in[21];
  const float* Wa  = (const float*)d_in[22]; const float* ba  = (const float*)d_in[23];
  const float* gamma = (const float*)d_in[24];
  const float* beta  = (const float*)d_in[25];
  const float* lam   = (const float*)d_in[26];
  const float* conv_w = (const float*)d_in[27];
  const float* conv_b = (const float*)d_in[28];
  float* out = (float*)d_out;

  const int M1 = Bc * Tt;       // 8200
  const int M2 = Bc * Ll;       // 2048
  const size_t BLA = (size_t)Bc * Ll * CA;
  const size_t BL2 = (size_t)Bc * Ll * 512;

  char* W = (char*)d_ws;
  u16*   qkvq  = (u16*)(W + 0);           // [8200][1792] = 29,388,800 B
  u16*   xb    = (u16*)(W + 29388800);    // bf16 x (att1 slot; dead after mega)
  u16*   att1  = (u16*)(W + 29388800);    // [8200][512]  =  8,396,800 B
  u16*   att2  = (u16*)(W + 29388800);    // reuse (att1 dead after o1)
  float* x_self= (float*)(W + 37785600);  // [8200][512] f32 = 16,793,600
  u16*   cat   = (u16*)(W + 54579200);    // [2048][512] = 2,097,152
  float* rzg   = (float*)(W + 56676352);  // [2048][512] f32 = 4,194,304
  float* addr_ = (float*)(W + 60870656);  // [2048][256] f32 = 2,097,152
  float* x_mem = (float*)(W + 54579200);  // reuse cat/rzg/addr after ln_gate
  u16*   gr_new= (u16*)(W + 62976000);    // [2048][256] = 1,048,576
  u16*   k2v2  = (u16*)(W + 64024576);    // [2048][512] = 2,097,152
  u16*   wtb   = (u16*)(W + 66121728);    // 3,538,944 B -> end 69,660,672

  u16* megaW = wtb;                 // [1792][512]
  u16* o1W   = wtb + 917504;        // [512][512]
  u16* rzW   = wtb + 1179648;       // [512][512]
  u16* aW    = wtb + 1441792;       // [256][512]
  u16* kvW   = wtb + 1572864;       // [512][256]
  u16* o2W   = wtb + 1703936;       // [256][256]

  const dim3 blk(256);

  // ---- weight casts into fused layouts ----
  {
    WCP p;
    p.w[0]  = {Wq1, megaW + 0,           512, 512, 9, 512 * 512};
    p.w[1]  = {Wk1, megaW + 512 * 512,   512, 512, 9, 512 * 512};
    p.w[2]  = {Wv1, megaW + 1024 * 512,  512, 512, 9, 512 * 512};
    p.w[3]  = {Wq2, megaW + 1536 * 512,  256, 256, 9, 256 * 512}; // zero-padded K
    p.w[4]  = {Wo1, o1W,                 512, 512, 9, 512 * 512};
    p.w[5]  = {Wr,  rzW + 0,             256, 512, 9, 256 * 512};
    p.w[6]  = {Wz,  rzW + 256 * 512,     256, 512, 9, 256 * 512};
    p.w[7]  = {Wa,  aW,                  256, 512, 9, 256 * 512};
    p.w[8]  = {Wk2, kvW + 0,             256, 256, 8, 256 * 256};
    p.w[9]  = {Wv2, kvW + 256 * 256,     256, 256, 8, 256 * 256};
    p.w[10] = {Wo2, o2W,                 256, 256, 8, 256 * 256};
    wcast_k<<<dim3(64, 11), blk, 0, stream>>>(p);
  }

  // ---- x -> bf16 (one-time) ----
  xcast_k<<<dim3(2050), blk, 0, stream>>>(x, xb);

  const float sQ1 = 0.18033688011112042f;   // (1/8) * log2(e)
  const float sQ2 = 0.25503490664918414f;   // (1/sqrt(32)) * log2(e)

  // ---- mega QKV1+Q2 projection: bf16 xb -> bf16 qkvq[8200][1792] ----
  {
    GemmEpi e;
    e.bias[0] = bq1; e.start[0] = 0;    e.scale[0] = sQ1;
    e.bias[1] = bk1; e.start[1] = 512;  e.scale[1] = 1.f;
    e.bias[2] = bv1; e.start[2] = 1024; e.scale[2] = 1.f;
    e.bias[3] = bq2; e.start[3] = 1536; e.scale[3] = sQ2;
    e.nreg = 4;
    gemm_mfma<1, EP_NONE, 1><<<dim3(14, 65), blk, 0, stream>>>(
        xb, 512, megaW, e, qkvq, M1, 1792, 512);
  }

  // ---- attention 1 ----
  attn_mfma<64><<<dim3(17, 64), dim3(256), 0, stream>>>(
      qkvq, qkvq + 512, qkvq + 1024, att1, Tt, Tt,
      Tt * 1792, Tt * 1792, Tt * 512, 1792, 1792, 512);

  // ---- o-proj 1 -> x_self fp32 ----
  {
    GemmEpi e; e.bias[0] = bo1; e.start[0] = 0; e.scale[0] = 1.f; e.nreg = 1;
    gemm_mfma<0, EP_NONE, 2><<<dim3(4, 65), blk, 0, stream>>>(
        att1, 512, o1W, e, x_self, M1, 512, 512);
  }

  // ---- GRU cache update ----
  build_cat<<<(int)((BL2 + 255) / 256), blk, 0, stream>>>(gr_cache, x_self, cat);
  {
    GemmEpi e;
    e.bias[0] = br; e.start[0] = 0;   e.scale[0] = 1.f;
    e.bias[1] = bz; e.start[1] = 256; e.scale[1] = 1.f;
    e.nreg = 2;
    gemm_mfma<0, EP_SIGMOID, 2><<<dim3(4, 16), blk, 0, stream>>>(
        cat, 512, rzW, e, rzg, M2, 512, 512);
  }
  build_cat2<<<(int)((BLA + 255) / 256), blk, 0, stream>>>(gr_cache, rzg, cat);
  {
    GemmEpi e; e.bias[0] = ba; e.start[0] = 0; e.scale[0] = 1.f; e.nreg = 1;
    gemm_mfma<0, EP_GELU, 2><<<dim3(2, 16), blk, 0, stream>>>(
        cat, 512, aW, e, addr_, M2, 256, 512);
  }
  ln_gate<<<M2, blk, 0, stream>>>(addr_, rzg, gr_cache, gamma, beta, gr_new);

  // ---- K2|V2 projection (fused) ----
  {
    GemmEpi e;
    e.bias[0] = bk2; e.start[0] = 0;   e.scale[0] = 1.f;
    e.bias[1] = bv2; e.start[1] = 256; e.scale[1] = 1.f;
    e.nreg = 2;
    gemm_mfma<1, EP_NONE, 2><<<dim3(4, 16), blk, 0, stream>>>(
        gr_new, 256, kvW, e, k2v2, M2, 512, 256);
  }

  // ---- attention 2 (q from qkvq cols 1536.., kv from k2v2) ----
  attn_mfma<32><<<dim3(17, 64), dim3(256), 0, stream>>>(
      qkvq + 1536, k2v2, k2v2 + 256, att2, Tt, Ll,
      Tt * 1792, Ll * 512, Tt * 256, 1792, 512, 256);

  // ---- o-proj 2 -> x_mem fp32 ----
  {
    GemmEpi e; e.bias[0] = bo2; e.start[0] = 0; e.scale[0] = 1.f; e.nreg = 1;
    gemm_mfma<0, EP_NONE, 2><<<dim3(2, 65), blk, 0, stream>>>(
        att2, 256, o2W, e, x_mem, M1, 256, 256);
  }

  // ---- fused conv(pos) + final mix -> d_out ----
  conv_combine<<<dim3(Bc * 32, 2), blk, 0, stream>>>(x, conv_w, conv_b, x_self,
                                                     x_mem, lam, out);
}